// Round 9
// baseline (95.074 us; speedup 1.0000x reference)
//
#include <hip/hip_runtime.h>
#include <math.h>

typedef _Float16 f16;
typedef __attribute__((ext_vector_type(8))) _Float16 f16x8;
typedef __attribute__((ext_vector_type(16))) float f32x16;

// sat (128,4,64,16) f32, grd (128,4,64,16) f32
// out (f32): sat 524288 | grd 524288 | distance[g][s] 16384 | orien[s][g] 16384
#define DIST_OFF  1048576
#define ORI_OFF   1064960
#define GRD_OFF   524288
#define SATP_STR  72          // f16 elems per satP row (144 B)
#define RSTR      66          // red j-stride: float2 -> 2-way banks (free)

#define MFMA(a,b,c) __builtin_amdgcn_mfma_f32_32x32x16_f16((a),(b),(c),0,0,0)

// ---- prep: grd -> frag-ready grdF[kb][g][e] hi/lo (k = dw*64 + h*16 + c) ----
__global__ __launch_bounds__(256) void prep_k(const float* __restrict__ grd,
                                              f16* __restrict__ gHi, f16* __restrict__ gLo) {
    __shared__ f16 tH[8192], tL[8192];          // [kb_l 64][g_l 16][e 8]
    const int b = blockIdx.x;
    const int tid = threadIdx.x;
    const int g0 = (b & 7) * 16;
    const int kq = b >> 3;                      // k-range [kq*512, kq*512+512)
    #pragma unroll
    for (int i = 0; i < 32; ++i) {
        int flat = i * 256 + tid;               // [g_l 16][h 4][j 128], coalesced reads
        int g_l = flat >> 9;
        int r   = flat & 511;
        int h   = r >> 7;
        int j   = r & 127;                      // dw_l = j>>4, c = j&15
        float v = grd[(((g0 + g_l) * 4 + h) * 64 + kq * 8) * 16 + j];
        int k_l = (j >> 4) * 64 + h * 16 + (j & 15);
        f16 hv = (f16)v;
        int a = (k_l >> 3) * 128 + g_l * 8 + (k_l & 7);
        tH[a] = hv;
        tL[a] = (f16)(v - (float)hv);
    }
    __syncthreads();
    #pragma unroll
    for (int i = 0; i < 4; ++i) {
        int f = i * 256 + tid;                  // frag: kb_l = f>>4, g_l = f&15
        int dst = (kq * 64 + (f >> 4)) * 128 + g0 + (f & 15);
        ((f16x8*)gHi)[dst] = *(const f16x8*)(tH + f * 8);
        ((f16x8*)gLo)[dst] = *(const f16x8*)(tL + f * 8);
    }
}

// ---- corr: grid 1024 = (s<<3)|(gq<<1)|jh; 512 thr = 8 waves (pure K-split) ----
// wave tile 32j x 32g, ~60 VGPR -> 8 waves/SIMD, 4 blocks/CU (37 KB LDS each).
// Emits per-(s,jh,g) argmax partials + per-s norm; combined in copy_k.
__global__ __launch_bounds__(512, 8) void corr_k(const float* __restrict__ sat,
                                                 const f16* __restrict__ gHi,
                                                 const f16* __restrict__ gLo,
                                                 float2* __restrict__ part,
                                                 float* __restrict__ norms) {
    __shared__ __align__(16) unsigned char smem[36864];  // satP 36.6KB | red 4x32x66 f32
    __shared__ float wred[8];
    f16* sH = (f16*)smem;                 // [w' 0..126][hc 0..63], stride 72
    f16* sL = sH + 127 * SATP_STR;        // byte offset 18288 from sH (ds imm ok)
    float* red = (float*)smem;            // [slot 4][g 32][j stride 66]

    const int tid = threadIdx.x;
    const int bi = blockIdx.x;
    const int s  = bi >> 3;
    const int gq = (bi >> 1) & 3;
    const int jh = bi & 1;
    const int kh = tid >> 6, lane = tid & 63;
    const int m = lane & 31, half = lane >> 5;

    // ---- stage satP hi/lo (doubled along w) + ||sat[s]||^2 ----
    const float* satS = sat + s * 4096;
    float ssq = 0.f;
    #pragma unroll
    for (int r = 0; r < 8; ++r) {
        int idx = r * 512 + tid;
        float v = satS[idx];
        int h = idx >> 10, w = (idx >> 4) & 63, c = idx & 15;
        int col = h * 16 + c;
        f16 hv = (f16)v, lv = (f16)(v - (float)hv);
        sH[w * SATP_STR + col] = hv;
        sL[w * SATP_STR + col] = lv;
        if (w < 63) { sH[(w + 64) * SATP_STR + col] = hv; sL[(w + 64) * SATP_STR + col] = lv; }
        ssq += v * v;
    }
    #pragma unroll
    for (int off = 32; off > 0; off >>= 1) ssq += __shfl_down(ssq, off, 64);
    if (lane == 0) wred[kh] = ssq;
    __syncthreads();
    if (tid == 0 && gq == 0 && jh == 0) {
        float t = 0.f;
        #pragma unroll
        for (int i = 0; i < 8; ++i) t += wred[i];
        norms[s] = sqrtf(t);
    }

    // ---- K-loop: wave kh owns 32 k-tiles; 2 ds_b128 + 2 global_x4 + 3 MFMA per tile ----
    const f16* Ah = sH + (jh * 32 + m) * SATP_STR + half * 8;
    const f16* Al = Ah + 127 * SATP_STR;                       // sL mirror, imm-able
    const f16x8* BH = (const f16x8*)gHi + half * 128 + gq * 32 + m;
    const f16x8* BL = (const f16x8*)gLo + half * 128 + gq * 32 + m;

    f32x16 accH, accX;
    #pragma unroll
    for (int r = 0; r < 16; ++r) { accH[r] = 0.f; accX[r] = 0.f; }

    const int t0 = kh * 32;
    #pragma unroll 8
    for (int i = 0; i < 32; ++i) {
        int t = t0 + i;
        int ao = (t >> 2) * SATP_STR + (t & 3) * 16;
        f16x8 ah = *(const f16x8*)(Ah + ao);     // ds_read_b128
        f16x8 al = *(const f16x8*)(Al + ao);
        f16x8 bh = BH[t * 256];                  // global dwordx4 (L2-resident)
        f16x8 bl = BL[t * 256];
        accH = MFMA(ah, bh, accH);
        accX = MFMA(ah, bl, accX);
        accX = MFMA(al, bh, accX);
    }
    accH = accH + accX;

    // ---- reduce 8 partials -> 4 slots -> sum (satP dead; red reuses smem) ----
    __syncthreads();
    {
        float* row = red + ((kh & 3) * 2112) + m * RSTR + half * 4;
        if (kh >= 4) {
            #pragma unroll
            for (int q = 0; q < 4; ++q) {
                *(float2*)(row + q * 8)     = (float2){ accH[4*q],   accH[4*q+1] };
                *(float2*)(row + q * 8 + 2) = (float2){ accH[4*q+2], accH[4*q+3] };
            }
        }
    }
    __syncthreads();
    if (kh < 4) {
        float* row = red + kh * 2112 + m * RSTR + half * 4;
        #pragma unroll
        for (int q = 0; q < 4; ++q) {
            float2 a = *(float2*)(row + q * 8), b = *(float2*)(row + q * 8 + 2);
            a.x += accH[4*q];   a.y += accH[4*q+1];
            b.x += accH[4*q+2]; b.y += accH[4*q+3];
            *(float2*)(row + q * 8)     = a;
            *(float2*)(row + q * 8 + 2) = b;
        }
    }
    __syncthreads();
    {
        int g = tid >> 4, j0 = (tid & 15) * 4;               // 512 thr = 32g x 16 j-quads
        int base = g * RSTR + j0;
        float2 u = {0.f, 0.f}, v = {0.f, 0.f};
        #pragma unroll
        for (int k = 0; k < 4; ++k) {
            float2 a = *(const float2*)(red + k * 2112 + base);
            float2 b = *(const float2*)(red + k * 2112 + base + 2);
            u.x += a.x; u.y += a.y; v.x += b.x; v.y += b.y;
        }
        *(float2*)(red + base) = u;           // own cells only: race-free
        *(float2*)(red + base + 2) = v;
    }
    __syncthreads();

    // ---- per-(jh) argmax over 32 j (ascending = first occurrence) ----
    if (tid < 32) {
        int g = tid;
        const float* row = red + g * RSTR;
        float best = row[0];
        int bj = 0;
        for (int j = 1; j < 32; ++j) {
            float v = row[j];
            if (v > best) { best = v; bj = j; }
        }
        part[(s * 2 + jh) * 128 + gq * 32 + g] = (float2){ best, (float)(jh * 32 + bj) };
    }
}

// ---- copy + combine: blocks <512 passthrough copies; 512..575 final argmax merge ----
__global__ void copy_k(const float4* __restrict__ a, const float4* __restrict__ b,
                       float4* __restrict__ out4,
                       const float2* __restrict__ part, const float* __restrict__ norms,
                       float* __restrict__ out) {
    const int bi = blockIdx.x;
    if (bi < 512) {
        int i = bi * 256 + threadIdx.x;
        out4[i] = a[i];
        out4[131072 + i] = b[i];
        return;
    }
    int i = (bi - 512) * 256 + threadIdx.x;    // 0..16383 = (s, g)
    int s = i >> 7, g = i & 127;
    float2 p0 = part[(s * 2 + 0) * 128 + g];
    float2 p1 = part[(s * 2 + 1) * 128 + g];
    float best = p0.x, bj = p0.y;
    if (p1.x > p0.x) { best = p1.x; bj = p1.y; }    // tie -> jh0 = first occurrence
    float rn = 1.f / fmaxf(norms[s], 1e-12f);
    out[DIST_OFF + g * 128 + s] = 2.f - 2.f * best * rn;
    out[ORI_OFF + s * 128 + g]  = bj;
}

// Fallback-only combine (runs before copy when partials live inside d_out)
__global__ void combine_k(const float2* __restrict__ part, const float* __restrict__ norms,
                          float* __restrict__ out) {
    int i = blockIdx.x * 256 + threadIdx.x;    // 0..16383
    int s = i >> 7, g = i & 127;
    float2 p0 = part[(s * 2 + 0) * 128 + g];
    float2 p1 = part[(s * 2 + 1) * 128 + g];
    float best = p0.x, bj = p0.y;
    if (p1.x > p0.x) { best = p1.x; bj = p1.y; }
    float rn = 1.f / fmaxf(norms[s], 1e-12f);
    out[DIST_OFF + g * 128 + s] = 2.f - 2.f * best * rn;
    out[ORI_OFF + s * 128 + g]  = bj;
}

__global__ void copy_only_k(const float4* __restrict__ a, const float4* __restrict__ b,
                            float4* __restrict__ out4) {
    int i = blockIdx.x * 256 + threadIdx.x;
    out4[i] = a[i];
    out4[131072 + i] = b[i];
}

extern "C" void kernel_launch(void* const* d_in, const int* in_sizes, int n_in,
                              void* d_out, int out_size, void* d_ws, size_t ws_size,
                              hipStream_t stream) {
    const float* sat = (const float*)d_in[0];
    const float* grd = (const float*)d_in[1];
    float* out = (float*)d_out;

    const bool useWs = (ws_size >= (size_t)(2 * 1024 * 1024 + 140 * 1024));
    f16* gHi; f16* gLo; float2* part; float* norms;
    if (useWs) {
        gHi   = (f16*)d_ws;                          // 1 MB
        gLo   = gHi + 524288;                        // 1 MB
        part  = (float2*)(gLo + 524288);             // 128*2*128 float2 = 256 KB... (32K*8B)
        norms = (float*)(part + 32768);              // 512 B
    } else {
        gHi   = (f16*)out;                           // sat region as staging
        gLo   = (f16*)(out + 262144);
        part  = (float2*)(out + GRD_OFF);            // grd region: partials
        norms = (float*)(out + GRD_OFF + 65536);
    }

    prep_k<<<64, 256, 0, stream>>>(grd, gHi, gLo);
    corr_k<<<1024, 512, 0, stream>>>(sat, gHi, gLo, part, norms);
    if (useWs) {
        copy_k<<<576, 256, 0, stream>>>((const float4*)sat, (const float4*)grd,
                                        (float4*)out, part, norms, out);
    } else {
        combine_k<<<64, 256, 0, stream>>>(part, norms, out);
        copy_only_k<<<512, 256, 0, stream>>>((const float4*)sat, (const float4*)grd,
                                             (float4*)out);
    }
}